// Round 1
// baseline (3029.717 us; speedup 1.0000x reference)
//
#include <hip/hip_runtime.h>
#include <hip/hip_bf16.h>

#define TSEQ  200
#define BATCH 256
#define INDIM 32
#define HID   512
#define GATES 2048

typedef __bf16 bf16x8 __attribute__((ext_vector_type(8)));
typedef float  f32x4  __attribute__((ext_vector_type(4)));

// ---- workspace layout (bytes) ----
static constexpr size_t OFF_PW_IH0 = 0;          // 2048*32*2  = 128 KB
static constexpr size_t OFF_PW_HH0 = 0x20000;    // 2048*512*2 = 2 MB
static constexpr size_t OFF_PW_IH1 = 0x220000;   // 2 MB
static constexpr size_t OFF_PW_HH1 = 0x420000;   // 2 MB
static constexpr size_t OFF_B0     = 0x620000;   // 8 KB
static constexpr size_t OFF_B1     = 0x622000;   // 8 KB
static constexpr size_t OFF_H1B0   = 0x624000;   // 256 KB packed bf16 h
static constexpr size_t OFF_H1B1   = 0x664000;
static constexpr size_t OFF_H2B0   = 0x6A4000;
static constexpr size_t OFF_H2B1   = 0x6E4000;
static constexpr size_t OFF_C1     = 0x724000;   // 512 KB fp32
static constexpr size_t OFF_C2     = 0x7A4000;   // 512 KB fp32
static constexpr size_t OFF_H2P    = 0x824000;   // 512 KB fp32 (final h2)
static constexpr size_t STATE_OFF  = OFF_H1B0;
static constexpr size_t STATE_LEN  = OFF_H2P - OFF_H1B0;  // zero h bufs + c states

__device__ __forceinline__ float sigm(float v) { return 1.f / (1.f + __expf(-v)); }

// Pack weight matrix W[2048][K] (fp32, row-major) into MFMA B-fragment order (bf16).
// Fragment index layout: frag[( (bn*8 + lnt)*KT + kt )*64 + lane][j], KT = K/32.
// lnt = type*2 + half; weight row g = type*512 + bn*32 + half*16 + (lane&15);
// weight col k = kt*32 + (lane>>4)*8 + j.
__global__ void pack_w(const float* __restrict__ W, __bf16* __restrict__ out, int ktlog2)
{
    int tid = blockIdx.x * 256 + threadIdx.x;          // one per bf16 element
    int K = 32 << ktlog2;
    int j    = tid & 7;
    int lane = (tid >> 3) & 63;
    int rest = tid >> 9;                                // (bn*8+lnt)*KT + kt
    int kt   = rest & ((1 << ktlog2) - 1);
    int r2   = rest >> ktlog2;                          // bn*8 + lnt
    int lnt  = r2 & 7;
    int bn   = r2 >> 3;
    int type = lnt >> 1, half = lnt & 1;
    int g    = type * 512 + bn * 32 + half * 16 + (lane & 15);
    int kcol = kt * 32 + (lane >> 4) * 8 + j;
    out[tid] = (__bf16)W[g * K + kcol];
}

__global__ void bias_comb(const float* __restrict__ a0, const float* __restrict__ a1,
                          const float* __restrict__ a2, const float* __restrict__ a3,
                          float* __restrict__ o0, float* __restrict__ o1)
{
    int tid = blockIdx.x * 256 + threadIdx.x;
    if (tid < GATES) { o0[tid] = a0[tid] + a1[tid]; o1[tid] = a2[tid] + a3[tid]; }
}

// One pipelined step: blocks 0..127 do layer0 step t=k (k<200),
// blocks 128..255 do layer1 step t=k-1 (k>=1).
// Block tile: 32 batches (2 m-tiles) x 32 hidden (all 4 gate types).
// Wave (of 4): wid -> (mt = mtb*2 + (wid>>1), half = wid&1); owns 4 type-tiles -> update is wave-local.
__global__ __launch_bounds__(256) void lstm_step(const float* __restrict__ x,
                                                 char* __restrict__ ws, int k)
{
    const int layer = blockIdx.x >> 7;
    if (layer == 0) { if (k >= TSEQ) return; }
    else            { if (k == 0)    return; }
    const int lb   = blockIdx.x & 127;
    const int mtb  = lb >> 4;        // 0..7  -> batches [mtb*32, +32)
    const int bn   = lb & 15;        // 0..15 -> hidden  [bn*32, +32)
    const int wid  = threadIdx.x >> 6;
    const int lane = threadIdx.x & 63;
    const int mt   = mtb * 2 + (wid >> 1);   // 16-batch tile, 0..15
    const int half = wid & 1;
    const int t    = k - layer;
    const int q    = lane >> 4;
    const int c16  = lane & 15;
    const int rd   = (k + 1) & 1;    // ping-pong read index
    const int wr   = k & 1;

    f32x4 acc[4] = {};               // [type] x 4 rows

    if (layer == 0) {
        const bf16x8* __restrict__ pBx = (const bf16x8*)(ws + OFF_PW_IH0);
        const bf16x8* __restrict__ pBh = (const bf16x8*)(ws + OFF_PW_HH0);
        const bf16x8* __restrict__ pA  = (const bf16x8*)(ws + (rd ? OFF_H1B1 : OFF_H1B0));
        // x contribution (K=32, one k-tile), A built from global x directly
        {
            const int b = mt * 16 + c16;
            const float* xp = x + ((size_t)b * TSEQ + t) * INDIM + q * 8;
            float4 xlo = *(const float4*)xp;
            float4 xhi = *(const float4*)(xp + 4);
            bf16x8 ax;
            ax[0] = (__bf16)xlo.x; ax[1] = (__bf16)xlo.y; ax[2] = (__bf16)xlo.z; ax[3] = (__bf16)xlo.w;
            ax[4] = (__bf16)xhi.x; ax[5] = (__bf16)xhi.y; ax[6] = (__bf16)xhi.z; ax[7] = (__bf16)xhi.w;
            #pragma unroll
            for (int ty = 0; ty < 4; ++ty) {
                bf16x8 bf = pBx[(bn * 8 + ty * 2 + half) * 64 + lane];
                acc[ty] = __builtin_amdgcn_mfma_f32_16x16x32_bf16(ax, bf, acc[ty], 0, 0, 0);
            }
        }
        // h contribution (K=512)
        #pragma unroll 4
        for (int kt = 0; kt < 16; ++kt) {
            bf16x8 a = pA[(mt * 16 + kt) * 64 + lane];
            #pragma unroll
            for (int ty = 0; ty < 4; ++ty) {
                bf16x8 bf = pBh[((((bn * 8 + ty * 2 + half)) << 4) + kt) * 64 + lane];
                acc[ty] = __builtin_amdgcn_mfma_f32_16x16x32_bf16(a, bf, acc[ty], 0, 0, 0);
            }
        }
    } else {
        const bf16x8* __restrict__ pB1 = (const bf16x8*)(ws + OFF_PW_IH1);
        const bf16x8* __restrict__ pB2 = (const bf16x8*)(ws + OFF_PW_HH1);
        const bf16x8* __restrict__ pA1 = (const bf16x8*)(ws + (rd ? OFF_H1B1 : OFF_H1B0));
        const bf16x8* __restrict__ pA2 = (const bf16x8*)(ws + (rd ? OFF_H2B1 : OFF_H2B0));
        #pragma unroll 4
        for (int kt = 0; kt < 16; ++kt) {
            bf16x8 a = pA1[(mt * 16 + kt) * 64 + lane];
            #pragma unroll
            for (int ty = 0; ty < 4; ++ty) {
                bf16x8 bf = pB1[((((bn * 8 + ty * 2 + half)) << 4) + kt) * 64 + lane];
                acc[ty] = __builtin_amdgcn_mfma_f32_16x16x32_bf16(a, bf, acc[ty], 0, 0, 0);
            }
        }
        #pragma unroll 4
        for (int kt = 0; kt < 16; ++kt) {
            bf16x8 a = pA2[(mt * 16 + kt) * 64 + lane];
            #pragma unroll
            for (int ty = 0; ty < 4; ++ty) {
                bf16x8 bf = pB2[((((bn * 8 + ty * 2 + half)) << 4) + kt) * 64 + lane];
                acc[ty] = __builtin_amdgcn_mfma_f32_16x16x32_bf16(a, bf, acc[ty], 0, 0, 0);
            }
        }
    }

    // ---- epilogue: gate nonlinearity + state update (wave-local) ----
    const float* __restrict__ bias = (const float*)(ws + (layer ? OFF_B1 : OFF_B0));
    float* __restrict__ cst = (float*)(ws + (layer ? OFF_C2 : OFF_C1));
    __bf16* __restrict__ hout = (__bf16*)(ws + (layer ? (wr ? OFF_H2B1 : OFF_H2B0)
                                                      : (wr ? OFF_H1B1 : OFF_H1B0)));
    float* __restrict__ h2p = (float*)(ws + OFF_H2P);

    const int hidx = bn * 32 + half * 16 + c16;       // C/D col = lane&15
    const float bi = bias[hidx];
    const float bf_ = bias[512 + hidx];
    const float bg = bias[1024 + hidx];
    const float bo = bias[1536 + hidx];
    const int kt_a = hidx >> 5;
    const int kk   = hidx & 31;
    const int qa   = kk >> 3, ja = kk & 7;

    #pragma unroll
    for (int r = 0; r < 4; ++r) {
        const int b = mt * 16 + q * 4 + r;            // C/D row = (lane>>4)*4 + reg
        float pi = acc[0][r] + bi;
        float pf = acc[1][r] + bf_;
        float pg = acc[2][r] + bg;
        float po = acc[3][r] + bo;
        float cold = cst[b * HID + hidx];
        float cn = sigm(pf) * cold + sigm(pi) * tanhf(pg);
        float hn = sigm(po) * tanhf(cn);
        cst[b * HID + hidx] = cn;
        // scatter into A-fragment-packed h buffer for next step's MFMA A loads
        hout[(((b >> 4) * 16 + kt_a) * 64 + qa * 16 + (b & 15)) * 8 + ja] = (__bf16)hn;
        if (layer == 1 && k == TSEQ) h2p[b * HID + hidx] = hn;
    }
}

// y = h2 @ w_fc.T + b_fc; p = sigmoid(y[:3]); r = normalize(tanh(y[3:]))
__global__ void fc_epilogue(const float* __restrict__ wfc, const float* __restrict__ bfc,
                            const char* __restrict__ ws, float* __restrict__ out)
{
    const int b = blockIdx.x;
    const int lane = threadIdx.x;   // 64
    const float* h = (const float*)(ws + OFF_H2P) + b * HID;
    float hv[8];
    #pragma unroll
    for (int j = 0; j < 8; ++j) hv[j] = h[lane * 8 + j];
    float y[7];
    #pragma unroll
    for (int o = 0; o < 7; ++o) {
        const float* wrow = wfc + o * HID;
        float s = 0.f;
        #pragma unroll
        for (int j = 0; j < 8; ++j) s += hv[j] * wrow[lane * 8 + j];
        #pragma unroll
        for (int off = 32; off >= 1; off >>= 1) s += __shfl_down(s, off);
        y[o] = s;
    }
    if (lane == 0) {
        out[b * 3 + 0] = sigm(y[0] + bfc[0]);
        out[b * 3 + 1] = sigm(y[1] + bfc[1]);
        out[b * 3 + 2] = sigm(y[2] + bfc[2]);
        float r0 = tanhf(y[3] + bfc[3]);
        float r1 = tanhf(y[4] + bfc[4]);
        float r2 = tanhf(y[5] + bfc[5]);
        float r3 = tanhf(y[6] + bfc[6]);
        float n = sqrtf(r0 * r0 + r1 * r1 + r2 * r2 + r3 * r3);
        n = fmaxf(n, 1e-12f);
        out[768 + b * 4 + 0] = r0 / n;
        out[768 + b * 4 + 1] = r1 / n;
        out[768 + b * 4 + 2] = r2 / n;
        out[768 + b * 4 + 3] = r3 / n;
    }
}

extern "C" void kernel_launch(void* const* d_in, const int* in_sizes, int n_in,
                              void* d_out, int out_size, void* d_ws, size_t ws_size,
                              hipStream_t stream)
{
    const float* x    = (const float*)d_in[0];
    const float* wih0 = (const float*)d_in[1];
    const float* whh0 = (const float*)d_in[2];
    const float* bih0 = (const float*)d_in[3];
    const float* bhh0 = (const float*)d_in[4];
    const float* wih1 = (const float*)d_in[5];
    const float* whh1 = (const float*)d_in[6];
    const float* bih1 = (const float*)d_in[7];
    const float* bhh1 = (const float*)d_in[8];
    const float* wfc  = (const float*)d_in[9];
    const float* bfc  = (const float*)d_in[10];
    char* ws = (char*)d_ws;

    // zero h/c state (ws is re-poisoned before every timed call)
    hipMemsetAsync(ws + STATE_OFF, 0, STATE_LEN, stream);

    // prologue: pack weights into MFMA fragment order (bf16), combine biases
    pack_w<<<256,  256, 0, stream>>>(wih0, (__bf16*)(ws + OFF_PW_IH0), 0);
    pack_w<<<4096, 256, 0, stream>>>(whh0, (__bf16*)(ws + OFF_PW_HH0), 4);
    pack_w<<<4096, 256, 0, stream>>>(wih1, (__bf16*)(ws + OFF_PW_IH1), 4);
    pack_w<<<4096, 256, 0, stream>>>(whh1, (__bf16*)(ws + OFF_PW_HH1), 4);
    bias_comb<<<8, 256, 0, stream>>>(bih0, bhh0, bih1, bhh1,
                                     (float*)(ws + OFF_B0), (float*)(ws + OFF_B1));

    // 201 pipelined steps: launch k runs layer0[t=k] and layer1[t=k-1]
    for (int k = 0; k <= TSEQ; ++k)
        lstm_step<<<256, 256, 0, stream>>>(x, ws, k);

    fc_epilogue<<<256, 64, 0, stream>>>(wfc, bfc, ws, (float*)d_out);
}